// Round 9
// baseline (425.929 us; speedup 1.0000x reference)
//
#include <hip/hip_runtime.h>
#include <cstdint>
#include <cstddef>

typedef __bf16 bf16;
typedef bf16 bf16x2 __attribute__((ext_vector_type(2)));
typedef bf16 bf16x4 __attribute__((ext_vector_type(4)));
typedef bf16 bf16x8 __attribute__((ext_vector_type(8)));
typedef float f32x4 __attribute__((ext_vector_type(4)));

// ---------------- graph preprocessing ----------------
__global__ void k_init(int* __restrict__ deg, int* __restrict__ cur,
                       float* __restrict__ sums1, float* __restrict__ sums2, int N) {
  int i = blockIdx.x * 256 + threadIdx.x;
  if (i < N) { deg[i] = 1; cur[i] = 0; }   // deg starts at 1: self loop
  if (i < 512)  sums1[i] = 0.f;
  if (i < 1024) sums2[i] = 0.f;
}

__global__ void k_count(const int* __restrict__ ei, int* __restrict__ deg, int E) {
  int e = blockIdx.x * 256 + threadIdx.x;
  if (e < E) atomicAdd(&deg[ei[E + e]], 1);   // dst = ei[E+e]
}

// hierarchical scan of (deg-1): scan1 block sums -> scan2 scans sums -> scan3 writes roff
__global__ __launch_bounds__(256) void k_scan1(const int* __restrict__ deg,
                                               int* __restrict__ bsum, int N) {
  int t = threadIdx.x;
  int i = blockIdx.x * 256 + t;
  int v = (i < N) ? deg[i] - 1 : 0;
#pragma unroll
  for (int off = 32; off > 0; off >>= 1) v += __shfl_down(v, off, 64);
  __shared__ int red[4];
  if ((t & 63) == 0) red[t >> 6] = v;
  __syncthreads();
  if (t == 0) bsum[blockIdx.x] = red[0] + red[1] + red[2] + red[3];
}

__global__ __launch_bounds__(256) void k_scan2(const int* __restrict__ bsum,
                                               int* __restrict__ bpre, int B) {
  __shared__ int s[256];
  int t = threadIdx.x;
  int v = (t < B) ? bsum[t] : 0;
  s[t] = v;
  __syncthreads();
  for (int off = 1; off < 256; off <<= 1) {
    int add = (t >= off) ? s[t - off] : 0;
    __syncthreads();
    s[t] += add;
    __syncthreads();
  }
  if (t < B) bpre[t] = s[t] - v;   // exclusive
}

__global__ __launch_bounds__(256) void k_scan3(const int* __restrict__ deg,
                                               const int* __restrict__ bpre,
                                               int* __restrict__ roff,
                                               float* __restrict__ dinv, int N) {
  __shared__ int s[256];
  int t = threadIdx.x;
  int i = blockIdx.x * 256 + t;
  int d = (i < N) ? deg[i] : 1;
  int v = d - 1;
  if (i >= N) v = 0;
  s[t] = v;
  __syncthreads();
  for (int off = 1; off < 256; off <<= 1) {
    int add = (t >= off) ? s[t - off] : 0;
    __syncthreads();
    s[t] += add;
    __syncthreads();
  }
  if (i < N) {
    int base = bpre[blockIdx.x];
    roff[i] = base + s[t] - v;
    dinv[i] = rsqrtf((float)d);
    if (i == N - 1) roff[N] = base + s[t];
  }
}

__global__ void k_scatter(const int* __restrict__ ei, const int* __restrict__ roff,
                          int* __restrict__ cur, int* __restrict__ csr, int E) {
  int e = blockIdx.x * 256 + threadIdx.x;
  if (e >= E) return;
  int d = ei[E + e];
  int p = atomicAdd(&cur[d], 1);
  csr[roff[d] + p] = ei[e];   // src
}

// ---------------- dtype conversion ----------------
__global__ void k_cvt_x(const float* __restrict__ x, bf16* __restrict__ xb, size_t total) {
  size_t base = ((size_t)blockIdx.x * 256 + threadIdx.x) * 4;
  if (base >= total) return;
  const float4 v = *(const float4*)(x + base);
  bf16x4 o;
  o[0] = (bf16)v.x; o[1] = (bf16)v.y; o[2] = (bf16)v.z; o[3] = (bf16)v.w;
  *(bf16x4*)(xb + base) = o;
}

// merged transpose+cast of all three weights: Wt[n][k] = W[k][n]
__global__ void k_cvt_w(const float* __restrict__ W1, const float* __restrict__ W2,
                        const float* __restrict__ Wl, bf16* __restrict__ w1t,
                        bf16* __restrict__ w2t, bf16* __restrict__ wlt) {
  int i = blockIdx.x * 256 + threadIdx.x;   // grid covers 229376 exactly
  if (i < 32768) {
    int n = i >> 7, k = i & 127;
    w1t[i] = (bf16)W1[(size_t)k * 256 + n];
  } else if (i < 163840) {
    int j = i - 32768;
    int n = j >> 8, k = j & 255;
    w2t[j] = (bf16)W2[(size_t)k * 512 + n];
  } else {
    int j = i - 163840;
    int n = j >> 9, k = j & 511;
    wlt[j] = (bf16)Wl[(size_t)k * 128 + n];
  }
}

// ---------------- bf16 MFMA GEMM: C[M,NOUT] = A[M,K] @ Bt[NOUT,K]^T ----------------
// R9 = R8 (XOR-swizzled LDS, 1 barrier/iter, reg staging) with:
//  (1) PREFETCH DISTANCE 2: register queue of two tile slots. Iter i writes
//      tile i to LDS (loaded at iter i-2 -> ~2 compute phases in flight,
//      covering ~900cyc HBM latency), then issues tile i+2. Compiler emits
//      s_waitcnt vmcnt(N>0): waits only the oldest loads (AITER pattern).
//      LDS race-free: compute(i-2) < barrier(i-1) < write(i) for all waves.
//      Full unroll (NIT compile-time) keeps queue indices constant.
//  (2) FINAL: BN2+ReLU fused into A-staging (t2 consumed raw; k_bnapply
//      deleted). Per-thread channels = k0 + j0*8 .. +7; scale/shift ride the
//      same distance-2 queue.
template<int K, int NOUT, bool FINAL>
__global__ __launch_bounds__(256) void k_gemm(const bf16* __restrict__ A,
                                              const bf16* __restrict__ Bt,
                                              bf16* __restrict__ outB,
                                              float* __restrict__ outF,
                                              const float* __restrict__ bias,
                                              float* __restrict__ sums,
                                              const float* __restrict__ bnsc,
                                              const float* __restrict__ bnsh,
                                              int Mreal) {
  constexpr int MT  = FINAL ? 64 : 128;   // m-tile rows
  constexpr int RPW = MT / 32;            // 16-row subtiles per wave
  constexpr int NIT = K / 32;             // K-loop iterations (>= 4 always)
  __shared__ uint4 lA[2][MT * 4];
  __shared__ uint4 lB[2][512];
  const int tid = threadIdx.x;
  const int wv = tid >> 6, lane = tid & 63;
  const int q = lane >> 4, mr = lane & 15;
  const int m0 = blockIdx.x * MT;
  const int n0 = blockIdx.y * 128;
  const int rw = (wv >> 1) * (MT / 2), cw = (wv & 1) * 64;

  // staging map: thread -> (row r0, k-chunk j0); 4 consecutive lanes = one 64B line
  const int r0 = tid >> 2, j0 = tid & 3;
  const bf16* gA0 = A + (size_t)(m0 + r0) * K + j0 * 8;
  const bf16* gA1 = A + (size_t)(m0 + 64 + r0) * K + j0 * 8;   // MT==128 only
  const bf16* gB0 = Bt + (size_t)(n0 + r0) * K + j0 * 8;
  const bf16* gB1 = Bt + (size_t)(n0 + 64 + r0) * K + j0 * 8;
  const int swz = j0 << 1;
  const int slA0 = j0 * MT + (r0 ^ swz);
  const int slA1 = j0 * MT + ((r0 + 64) ^ swz);                // MT==128 only
  const int slB0 = j0 * 128 + (r0 ^ swz);
  const int slB1 = j0 * 128 + ((r0 + 64) ^ swz);

  f32x4 acc[RPW][4];
#pragma unroll
  for (int r = 0; r < RPW; ++r)
#pragma unroll
    for (int c = 0; c < 4; ++c) acc[r][c] = (f32x4){0.f, 0.f, 0.f, 0.f};

  // distance-2 prefetch queue (slots 0,1 preloaded with tiles 0,1)
  uint4 qA0[2], qA1[2], qB0[2], qB1[2];
  float4 qsc[2][2], qsh[2][2];
#pragma unroll
  for (int t = 0; t < 2; ++t) {
    qA0[t] = *(const uint4*)(gA0 + t * 32);
    if constexpr (MT == 128) qA1[t] = *(const uint4*)(gA1 + t * 32);
    qB0[t] = *(const uint4*)(gB0 + t * 32);
    qB1[t] = *(const uint4*)(gB1 + t * 32);
    if constexpr (FINAL) {
      int cb = t * 32 + j0 * 8;
      qsc[t][0] = *(const float4*)(bnsc + cb);
      qsc[t][1] = *(const float4*)(bnsc + cb + 4);
      qsh[t][0] = *(const float4*)(bnsh + cb);
      qsh[t][1] = *(const float4*)(bnsh + cb + 4);
    }
  }

  const int qs = q << 1;   // read-side XOR key
#pragma unroll
  for (int i = 0; i < NIT; ++i) {
    const int sl = i & 1;
    // ---- write tile i (in regs since iter i-2) to LDS buf sl ----
    uint4 wA0 = qA0[sl];
    if constexpr (FINAL) {   // fused BN2+ReLU on the A (t2) data
      bf16x8 a = *(bf16x8*)&wA0;
      float s[8] = {qsc[sl][0].x, qsc[sl][0].y, qsc[sl][0].z, qsc[sl][0].w,
                    qsc[sl][1].x, qsc[sl][1].y, qsc[sl][1].z, qsc[sl][1].w};
      float h[8] = {qsh[sl][0].x, qsh[sl][0].y, qsh[sl][0].z, qsh[sl][0].w,
                    qsh[sl][1].x, qsh[sl][1].y, qsh[sl][1].z, qsh[sl][1].w};
#pragma unroll
      for (int u = 0; u < 8; ++u)
        a[u] = (bf16)fmaxf(0.f, (float)a[u] * s[u] + h[u]);
      wA0 = *(uint4*)&a;
    }
    lA[sl][slA0] = wA0;
    if constexpr (MT == 128) lA[sl][slA1] = qA1[sl];
    lB[sl][slB0] = qB0[sl];
    lB[sl][slB1] = qB1[sl];
    __syncthreads();
    // ---- issue tile i+2 into the freed slot ----
    if (i + 2 < NIT) {
      int kn = (i + 2) * 32;
      qA0[sl] = *(const uint4*)(gA0 + kn);
      if constexpr (MT == 128) qA1[sl] = *(const uint4*)(gA1 + kn);
      qB0[sl] = *(const uint4*)(gB0 + kn);
      qB1[sl] = *(const uint4*)(gB1 + kn);
      if constexpr (FINAL) {
        int cb = kn + j0 * 8;
        qsc[sl][0] = *(const float4*)(bnsc + cb);
        qsc[sl][1] = *(const float4*)(bnsc + cb + 4);
        qsh[sl][0] = *(const float4*)(bnsh + cb);
        qsh[sl][1] = *(const float4*)(bnsh + cb + 4);
      }
    }
    // ---- consume tile i ----
    bf16x8 af[RPW], bfr[4];
#pragma unroll
    for (int r = 0; r < RPW; ++r)
      af[r] = ((const bf16x8*)lA[sl])[q * MT + ((rw + r * 16 + mr) ^ qs)];
#pragma unroll
    for (int c = 0; c < 4; ++c)
      bfr[c] = ((const bf16x8*)lB[sl])[q * 128 + ((cw + c * 16 + mr) ^ qs)];
#pragma unroll
    for (int r = 0; r < RPW; ++r)
#pragma unroll
      for (int c = 0; c < 4; ++c)
        acc[r][c] = __builtin_amdgcn_mfma_f32_16x16x32_bf16(af[r], bfr[c], acc[r][c], 0, 0, 0);
  }

  // C/D layout: col = lane&15, row = (lane>>4)*4 + reg (m89/m91-verified)
#pragma unroll
  for (int c = 0; c < 4; ++c) {
    const int col = n0 + cw + c * 16 + mr;
    float s0 = 0.f, s1 = 0.f;
#pragma unroll
    for (int r = 0; r < RPW; ++r) {
#pragma unroll
      for (int i = 0; i < 4; ++i) {
        int row = m0 + rw + r * 16 + q * 4 + i;
        float v = acc[r][c][i];
        if (FINAL) {
          if (row < Mreal) outF[(size_t)row * NOUT + col] = v + bias[col];
        } else {
          outB[(size_t)row * NOUT + col] = (bf16)v;
          if (row < Mreal) { s0 += v; s1 += v * v; }
        }
      }
    }
    if (!FINAL) {
      s0 += __shfl_xor(s0, 16, 64); s0 += __shfl_xor(s0, 32, 64);
      s1 += __shfl_xor(s1, 16, 64); s1 += __shfl_xor(s1, 32, 64);
      if (q == 0) { atomicAdd(&sums[col], s0); atomicAdd(&sums[NOUT + col], s1); }
    }
  }
}

// ---------------- CSR aggregation (one wave per node) ----------------
// g[v] = dinv[v] * ( sum_e dinv[s]*f(h[s]) + dinv[v]*f(h[v]) )
// f = identity or fused BN+ReLU of prev layer (per-channel scale/shift in regs).
template<int C, bool BN>
__global__ __launch_bounds__(256) void k_agg(const bf16* __restrict__ h,
                                             bf16* __restrict__ g,
                                             const int* __restrict__ csr,
                                             const int* __restrict__ roff,
                                             const float* __restrict__ dinv,
                                             const float* __restrict__ scale,
                                             const float* __restrict__ shift,
                                             int N) {
  constexpr int VPL = C / 64;   // channels per lane: 2 or 4
  const int lane = threadIdx.x & 63;
  const int v = (int)(((unsigned)blockIdx.x * 256 + threadIdx.x) >> 6);
  if (v >= N) return;
  float sc[VPL], sh[VPL];
  if constexpr (BN) {
#pragma unroll
    for (int u = 0; u < VPL; ++u) { sc[u] = scale[lane * VPL + u]; sh[u] = shift[lane * VPL + u]; }
  }
  const float dv = dinv[v];
  float acc[VPL];
#pragma unroll
  for (int u = 0; u < VPL; ++u) acc[u] = 0.f;

  auto accum = [&](int src, float w) {
    const bf16* hr = h + (size_t)src * C + lane * VPL;
    float vals[VPL];
    if constexpr (VPL == 2) {
      bf16x2 t = *(const bf16x2*)hr;
      vals[0] = (float)t[0]; vals[1] = (float)t[1];
    } else {
      bf16x4 t = *(const bf16x4*)hr;
#pragma unroll
      for (int u = 0; u < 4; ++u) vals[u] = (float)t[u];
    }
#pragma unroll
    for (int u = 0; u < VPL; ++u) {
      float xx = vals[u];
      if constexpr (BN) xx = fmaxf(0.f, xx * sc[u] + sh[u]);
      acc[u] += w * xx;
    }
  };

  accum(v, dv);   // self loop (becomes dv^2 after final *dv)
  const int beg = roff[v], end = roff[v + 1];
  for (int base = beg; base < end; base += 64) {
    int cnt = min(64, end - base);
    int s = 0; float w = 0.f;
    if (lane < cnt) { s = csr[base + lane]; w = dinv[s]; }
    for (int j = 0; j < cnt; ++j) {
      int sj = __shfl(s, j, 64);
      float wj = __shfl(w, j, 64);
      accum(sj, wj);
    }
  }

  bf16* gv = g + (size_t)v * C + lane * VPL;
  if constexpr (VPL == 2) {
    bf16x2 o;
    o[0] = (bf16)(acc[0] * dv); o[1] = (bf16)(acc[1] * dv);
    *(bf16x2*)gv = o;
  } else {
    bf16x4 o;
#pragma unroll
    for (int u = 0; u < 4; ++u) o[u] = (bf16)(acc[u] * dv);
    *(bf16x4*)gv = o;
  }
}

// ---------------- BatchNorm ----------------
__global__ void k_bnfinal(const float* __restrict__ sums, const float* __restrict__ gamma,
                          const float* __restrict__ beta, float* __restrict__ scale,
                          float* __restrict__ shift, int C, float invN) {
  int c = blockIdx.x * 256 + threadIdx.x;
  if (c >= C) return;
  float mu = sums[c] * invN;
  float var = sums[C + c] * invN - mu * mu;   // biased var (ddof=0)
  float is = rsqrtf(var + 1e-5f);
  float sc = gamma[c] * is;
  scale[c] = sc;
  shift[c] = beta[c] - mu * sc;
}

// ---------------- launch ----------------
extern "C" void kernel_launch(void* const* d_in, const int* in_sizes, int n_in,
                              void* d_out, int out_size, void* d_ws, size_t ws_size,
                              hipStream_t stream) {
  const float* x   = (const float*)d_in[0];
  const int*   ei  = (const int*)d_in[1];
  const float* W1  = (const float*)d_in[2];
  // d_in[3] = b1: absorbed by BN (mean subtraction cancels it)
  const float* g1  = (const float*)d_in[4];
  const float* be1 = (const float*)d_in[5];
  const float* W2  = (const float*)d_in[6];
  // d_in[7] = b2: absorbed by BN
  const float* g2  = (const float*)d_in[8];
  const float* be2 = (const float*)d_in[9];
  const float* Wl  = (const float*)d_in[10];
  const float* bl  = (const float*)d_in[11];
  float* out = (float*)d_out;

  const int N  = in_sizes[0] / 128;          // 50000
  const int E  = in_sizes[1] / 2;            // 500000
  const int Mp = ((N + 127) / 128) * 128;    // 50048 = 391*128 = 782*64
  const int NB = (N + 255) / 256;            // scan blocks (196)

  char* p = (char*)d_ws;
  auto carve = [&](size_t bytes) { void* r = (void*)p; p += (bytes + 255) & ~(size_t)255; return r; };
  int*   deg   = (int*)carve(sizeof(int) * N);
  int*   cur   = (int*)carve(sizeof(int) * N);
  int*   roff  = (int*)carve(sizeof(int) * (N + 1));
  int*   csr   = (int*)carve(sizeof(int) * E);
  int*   bsum  = (int*)carve(sizeof(int) * 256);
  int*   bpre  = (int*)carve(sizeof(int) * 256);
  float* dinv  = (float*)carve(sizeof(float) * N);
  float* sums1 = (float*)carve(sizeof(float) * 512);
  float* sums2 = (float*)carve(sizeof(float) * 1024);
  float* sc1   = (float*)carve(sizeof(float) * 256);
  float* sh1   = (float*)carve(sizeof(float) * 256);
  float* sc2   = (float*)carve(sizeof(float) * 512);
  float* sh2   = (float*)carve(sizeof(float) * 512);
  bf16*  w1t   = (bf16*)carve(sizeof(bf16) * 256 * 128);
  bf16*  w2t   = (bf16*)carve(sizeof(bf16) * 512 * 256);
  bf16*  wlt   = (bf16*)carve(sizeof(bf16) * 128 * 512);
  bf16*  xb    = (bf16*)carve(sizeof(bf16) * (size_t)Mp * 128);
  bf16*  ax1   = (bf16*)carve(sizeof(bf16) * (size_t)Mp * 128);  // agg(x)
  bf16*  t1    = (bf16*)carve(sizeof(bf16) * (size_t)Mp * 256);  // ax1 @ W1
  bf16*  ax2   = (bf16*)carve(sizeof(bf16) * (size_t)Mp * 256);  // agg(relu(bn(t1)))
  bf16*  t2    = (bf16*)carve(sizeof(bf16) * (size_t)Mp * 512);  // ax2 @ W2 (raw pre-BN)
  (void)n_in; (void)out_size; (void)ws_size;

  const int gE = (E + 255) / 256;
  k_init<<<NB, 256, 0, stream>>>(deg, cur, sums1, sums2, N);
  k_count<<<gE, 256, 0, stream>>>(ei, deg, E);
  k_scan1<<<NB, 256, 0, stream>>>(deg, bsum, N);
  k_scan2<<<1, 256, 0, stream>>>(bsum, bpre, NB);
  k_scan3<<<NB, 256, 0, stream>>>(deg, bpre, roff, dinv, N);   // dinv fused
  k_scatter<<<gE, 256, 0, stream>>>(ei, roff, cur, csr, E);

  k_cvt_x<<<(int)(((size_t)N * 128 / 4 + 255) / 256), 256, 0, stream>>>(x, xb, (size_t)N * 128);
  k_cvt_w<<<896, 256, 0, stream>>>(W1, W2, Wl, w1t, w2t, wlt);

  const int gAgg = (N + 3) / 4;
  // layer 1: aggregate first (S commutes with dense transform), then GEMM(+stats)
  k_agg<128, false><<<gAgg, 256, 0, stream>>>(xb, ax1, csr, roff, dinv, nullptr, nullptr, N);
  k_gemm<128, 256, false><<<dim3(Mp / 128, 2), 256, 0, stream>>>(ax1, w1t, t1, nullptr, nullptr, sums1, nullptr, nullptr, N);
  k_bnfinal<<<1, 256, 0, stream>>>(sums1, g1, be1, sc1, sh1, 256, 1.f / (float)N);

  // layer 2: gather applies BN1+ReLU on the fly
  k_agg<256, true><<<gAgg, 256, 0, stream>>>(t1, ax2, csr, roff, dinv, sc1, sh1, N);
  k_gemm<256, 512, false><<<dim3(Mp / 128, 4), 256, 0, stream>>>(ax2, w2t, t2, nullptr, nullptr, sums2, nullptr, nullptr, N);
  k_bnfinal<<<2, 256, 0, stream>>>(sums2, g2, be2, sc2, sh2, 512, 1.f / (float)N);

  // final linear: out = relu(bn(t2)) @ Wl + bl — BN2+ReLU fused into A-staging
  k_gemm<512, 128, true><<<dim3(Mp / 64, 1), 256, 0, stream>>>(t2, wlt, nullptr, out, bl, nullptr, sc2, sh2, N);
}